// Round 4
// baseline (160.565 us; speedup 1.0000x reference)
//
#include <hip/hip_runtime.h>
#include <hip/hip_bf16.h>

typedef __attribute__((ext_vector_type(8))) short bf16x8;
typedef __attribute__((ext_vector_type(4))) float f32x4;
typedef __attribute__((ext_vector_type(16))) float f32x16;
typedef __attribute__((ext_vector_type(4))) unsigned short u16x4;
typedef __attribute__((ext_vector_type(4))) unsigned int u32x4;

#define NB 2
#define NS 4096
#define ND 512
#define NH 8

__device__ __forceinline__ unsigned short f2bf(float f) {
  unsigned int u = __float_as_uint(f);
  u += 0x7fffu + ((u >> 16) & 1u);
  return (unsigned short)(u >> 16);
}

__device__ __forceinline__ float bf2f(unsigned short h) {
  return __uint_as_float(((unsigned)h) << 16);
}

__device__ __forceinline__ float exp2_hw(float x) {
  float r;
  asm("v_exp_f32 %0, %1" : "=v"(r) : "v"(x));
  return r;
}

__device__ __forceinline__ unsigned cvtpk(float lo, float hi) {
  unsigned r;
  asm("v_cvt_pk_bf16_f32 %0, %1, %2" : "=v"(r) : "v"(lo), "v"(hi));
  return r;
}

__device__ __forceinline__ void swap32(unsigned& a, unsigned& b) {
  asm("v_permlane32_swap_b32 %0, %1" : "+v"(a), "+v"(b));
}

__device__ __forceinline__ bf16x8 mkfrag(unsigned w0, unsigned w1,
                                         unsigned w2, unsigned w3) {
  u32x4 u = {w0, w1, w2, w3};
  return __builtin_bit_cast(bf16x8, u);
}

// ---------------- pack: fp32 -> bf16, pre-transpose weights ----------------
__global__ void pack_kernel(const float* __restrict__ x,
                            const float* __restrict__ Wq,
                            const float* __restrict__ Wk,
                            const float* __restrict__ Wv,
                            const float* __restrict__ Wo,
                            unsigned short* __restrict__ x_bf,
                            unsigned short* __restrict__ w3,    // [3*512][512]
                            unsigned short* __restrict__ wo_t)  // [512][512]
{
  int idx = blockIdx.x * 256 + threadIdx.x;
  const int NX4 = NB * NS * ND / 4;  // 1048576 float4s
  const int NW = 512 * 512;          // 262144
  if (idx < NX4) {
    const float4 f = ((const float4*)x)[idx];
    u16x4 o;
    o[0] = f2bf(f.x); o[1] = f2bf(f.y); o[2] = f2bf(f.z); o[3] = f2bf(f.w);
    ((u16x4*)x_bf)[idx] = o;
  } else if (idx < NX4 + 3 * NW) {
    int j = idx - NX4;
    int p = j / NW;
    int r = j - p * NW;
    int n = r >> 9, d = r & 511;
    int h = n >> 6, o = n & 63;
    const float* W = (p == 0) ? Wq : (p == 1) ? Wk : Wv;
    w3[j] = f2bf(W[(h * 512 + d) * 64 + o]);
  } else if (idx < NX4 + 4 * NW) {
    int j = idx - NX4 - 3 * NW;
    int n = j >> 9, kk = j & 511;
    wo_t[j] = f2bf(Wo[kk * 512 + n]);
  }
}

// ---------------- GEMM: C[m][n] = sum_k A[m][k]*Bm[n][k], K=512 ------------
template <int MODE>
__global__ void gemm_bt(const unsigned short* __restrict__ A,
                        const unsigned short* __restrict__ Bm,
                        const float* __restrict__ b0,
                        const float* __restrict__ b1,
                        const float* __restrict__ b2,
                        unsigned short* __restrict__ qo,
                        unsigned short* __restrict__ ko,
                        unsigned short* __restrict__ vo,
                        float* __restrict__ fo) {
  __shared__ unsigned short Al[128 * 32];
  __shared__ unsigned short Bl[128 * 32];
  const int t = threadIdx.x;
  const int m0 = blockIdx.x * 128;
  const int n0 = blockIdx.y * 128;
  const int lane = t & 63;
  const int w = t >> 6;
  const int wm = w >> 1, wn = w & 1;
  const int c = lane & 15, g = lane >> 4;

  f32x4 acc[4][4];
#pragma unroll
  for (int i = 0; i < 4; ++i)
#pragma unroll
    for (int j = 0; j < 4; ++j) acc[i][j] = (f32x4){0.f, 0.f, 0.f, 0.f};

  const int srow = t >> 1, sseg = (t & 1) * 16;
  const unsigned short* Ap = A + (size_t)(m0 + srow) * 512 + sseg;
  const unsigned short* Bp = Bm + (size_t)(n0 + srow) * 512 + sseg;
  unsigned short* Alp = &Al[srow * 32 + sseg];
  unsigned short* Blp = &Bl[srow * 32 + sseg];

  for (int k0 = 0; k0 < 512; k0 += 32) {
    bf16x8 ra0 = *(const bf16x8*)(Ap + k0);
    bf16x8 ra1 = *(const bf16x8*)(Ap + k0 + 8);
    bf16x8 rb0 = *(const bf16x8*)(Bp + k0);
    bf16x8 rb1 = *(const bf16x8*)(Bp + k0 + 8);
    __syncthreads();
    *(bf16x8*)(Alp) = ra0;
    *(bf16x8*)(Alp + 8) = ra1;
    *(bf16x8*)(Blp) = rb0;
    *(bf16x8*)(Blp + 8) = rb1;
    __syncthreads();
    bf16x8 af[4], bfr[4];
#pragma unroll
    for (int mf = 0; mf < 4; ++mf)
      af[mf] = *(const bf16x8*)&Al[(wm * 64 + mf * 16 + c) * 32 + g * 8];
#pragma unroll
    for (int nf = 0; nf < 4; ++nf)
      bfr[nf] = *(const bf16x8*)&Bl[(wn * 64 + nf * 16 + c) * 32 + g * 8];
#pragma unroll
    for (int mf = 0; mf < 4; ++mf)
#pragma unroll
      for (int nf = 0; nf < 4; ++nf)
        acc[mf][nf] = __builtin_amdgcn_mfma_f32_16x16x32_bf16(
            af[mf], bfr[nf], acc[mf][nf], 0, 0, 0);
  }

  if (MODE == 0) {
    const int proj = n0 >> 9;  // 0=q,1=k,2=v
    const float* bias = proj == 0 ? b0 : (proj == 1 ? b1 : b2);
    unsigned short* dst01 = proj == 0 ? qo : ko;
    // q pre-scale folds 1/sqrt(64) AND log2(e) so attention can use exp2
    const float scale = proj == 0 ? 0.18033688011112042f : 1.0f;
#pragma unroll
    for (int nf = 0; nf < 4; ++nf) {
      const int col5 = (n0 + wn * 64 + nf * 16 + c) & 511;
      const int h = col5 >> 6, o = col5 & 63;
      const float bb = bias[col5];
#pragma unroll
      for (int mf = 0; mf < 4; ++mf) {
#pragma unroll
        for (int r = 0; r < 4; ++r) {
          const int m = m0 + wm * 64 + mf * 16 + g * 4 + r;
          const int b = m >> 12, s = m & 4095;
          const unsigned short hb = f2bf((acc[mf][nf][r] + bb) * scale);
          if (proj < 2)
            dst01[((size_t)((b * NH + h) * NS + s)) * 64 + o] = hb;
          else
            vo[((size_t)((b * NH + h) * 64 + o)) * NS + s] = hb;
        }
      }
    }
  } else {
#pragma unroll
    for (int nf = 0; nf < 4; ++nf) {
      const int col = n0 + wn * 64 + nf * 16 + c;
      const float bb = b0[col];
#pragma unroll
      for (int mf = 0; mf < 4; ++mf) {
#pragma unroll
        for (int r = 0; r < 4; ++r) {
          const int m = m0 + wm * 64 + mf * 16 + g * 4 + r;
          fo[(size_t)m * 512 + col] = acc[mf][nf][r] + bb;
        }
      }
    }
  }
}

// ------- flash attention v4: swapped-operand 32x32x16 + KV-split ----------
// SPLITS=2: blockIdx.y = sp*16 + bh; each block does 128 q-rows x 2048 keys,
// writes unnormalized O^T (bf16) + (m,l) partials. SPLITS=1: direct output.
template <int SPLITS>
__global__ __launch_bounds__(256, 4) void attn_kernel(
    const unsigned short* __restrict__ q,     // [bh][s][64] (pre-scaled)
    const unsigned short* __restrict__ k,     // [bh][s][64]
    const unsigned short* __restrict__ vt,    // [bh][64][s]
    unsigned short* __restrict__ cc,          // [b][s][512]      (SPLITS=1)
    unsigned short* __restrict__ op,          // [sp][bh][s][64]  (SPLITS=2)
    float* __restrict__ ml)                   // [sp][bh][s][2]   (SPLITS=2)
{
  union SMemU {
    struct { unsigned short Kl[2][4096]; unsigned short Vl[2][4096]; } kv;
    unsigned short Ol[4][32][68];  // epilogue transpose (K/V dead by then)
  };
  __shared__ SMemU sm;
  const int t = threadIdx.x;
  const int w = t >> 6, lane = t & 63;
  const int col = lane & 31, hi = lane >> 5;
  const int bh = blockIdx.y & 15;
  const int sp = blockIdx.y >> 4;
  const int b = bh >> 3, h = bh & 7;
  const int q0 = blockIdx.x * 128 + w * 32;  // this wave's 32 q-rows
  const int kbase = sp * (NS / SPLITS);

  const unsigned short* qh = q + (size_t)bh * NS * 64;
  const unsigned short* kh = k + (size_t)bh * NS * 64;
  const unsigned short* vh = vt + (size_t)bh * 64 * NS;

  // Q as B-operand: lane: qrow=col, d = 16c + 8*hi + j
  bf16x8 qf[4];
#pragma unroll
  for (int c = 0; c < 4; ++c)
    qf[c] = *(const bf16x8*)&qh[(size_t)(q0 + col) * 64 + c * 16 + hi * 8];

  // staging geometry (proven layout)
  const int r0 = t >> 3, r1 = r0 + 32;
  const int ch = t & 7;
  const int koff0 = r0 * 64 + ((ch ^ (r0 & 7)) << 3);
  const int koff1 = r1 * 64 + ((ch ^ (r1 & 7)) << 3);

  f32x16 ot0, ot1;
#pragma unroll
  for (int r = 0; r < 16; ++r) { ot0[r] = 0.f; ot1[r] = 0.f; }
  float m_ = -1.0e30f, l_ = 0.f;

  {  // prologue: stage tile 0 into buffer 0
    bf16x8 a0 = *(const bf16x8*)&kh[(size_t)(kbase + r0) * 64 + ch * 8];
    bf16x8 a1 = *(const bf16x8*)&kh[(size_t)(kbase + r1) * 64 + ch * 8];
    bf16x8 v0 = *(const bf16x8*)&vh[(size_t)r0 * NS + kbase + ch * 8];
    bf16x8 v1 = *(const bf16x8*)&vh[(size_t)r1 * NS + kbase + ch * 8];
    *(bf16x8*)&sm.kv.Kl[0][koff0] = a0;
    *(bf16x8*)&sm.kv.Kl[0][koff1] = a1;
    *(bf16x8*)&sm.kv.Vl[0][koff0] = v0;
    *(bf16x8*)&sm.kv.Vl[0][koff1] = v1;
    __syncthreads();
  }

  const int NT = NS / (64 * SPLITS);
  for (int it = 0; it < NT; ++it) {
    const int cur = it & 1;
    bf16x8 pk0, pk1, pv0, pv1;
    if (it + 1 < NT) {
      const int tn = kbase + (it + 1) * 64;
      pk0 = *(const bf16x8*)&kh[(size_t)(tn + r0) * 64 + ch * 8];
      pk1 = *(const bf16x8*)&kh[(size_t)(tn + r1) * 64 + ch * 8];
      pv0 = *(const bf16x8*)&vh[(size_t)r0 * NS + tn + ch * 8];
      pv1 = *(const bf16x8*)&vh[(size_t)r1 * NS + tn + ch * 8];
    }

    // ---- S^T = K · Q^T : p0 = keys[0..31], p1 = keys[32..63] ----
    f32x16 p0, p1;
#pragma unroll
    for (int r = 0; r < 16; ++r) { p0[r] = 0.f; p1[r] = 0.f; }
#pragma unroll
    for (int c = 0; c < 4; ++c) {
      const int cidx = (((2 * c + hi) ^ (col & 7)) << 3);
      bf16x8 kf0 = *(const bf16x8*)&sm.kv.Kl[cur][col * 64 + cidx];
      bf16x8 kf1 = *(const bf16x8*)&sm.kv.Kl[cur][(col + 32) * 64 + cidx];
      p0 = __builtin_amdgcn_mfma_f32_32x32x16_bf16(kf0, qf[c], p0, 0, 0, 0);
      p1 = __builtin_amdgcn_mfma_f32_32x32x16_bf16(kf1, qf[c], p1, 0, 0, 0);
    }

    // ---- lane-local online softmax (log2 domain) ----
    float mx[8];
#pragma unroll
    for (int r = 0; r < 8; ++r)
      mx[r] = fmaxf(fmaxf(p0[r], p0[r + 8]), fmaxf(p1[r], p1[r + 8]));
#pragma unroll
    for (int s = 4; s >= 1; s >>= 1)
#pragma unroll
      for (int r = 0; r < 8; ++r)
        if (r < s) mx[r] = fmaxf(mx[r], mx[r + s]);
    float pm = mx[0];
    pm = fmaxf(pm, __shfl_xor(pm, 32, 64));
    if (__any(pm > m_ + 8.f)) {  // defer-max
      const float resc = exp2_hw(m_ - pm);
      m_ = pm;
      l_ *= resc;
#pragma unroll
      for (int r = 0; r < 16; ++r) { ot0[r] *= resc; ot1[r] *= resc; }
    }
    float e0[16], e1[16];
#pragma unroll
    for (int r = 0; r < 16; ++r) {
      e0[r] = exp2_hw(p0[r] - m_);
      e1[r] = exp2_hw(p1[r] - m_);
    }
    float smv[8];
#pragma unroll
    for (int r = 0; r < 8; ++r)
      smv[r] = (e0[r] + e0[r + 8]) + (e1[r] + e1[r + 8]);
#pragma unroll
    for (int s = 4; s >= 1; s >>= 1)
#pragma unroll
      for (int r = 0; r < 8; ++r)
        if (r < s) smv[r] += smv[r + s];
    float rs = smv[0];
    rs += __shfl_xor(rs, 32, 64);
    l_ += rs;

    // ---- P -> bf16 B-fragments in-register ----
    unsigned g0[8], g1[8];
#pragma unroll
    for (int gg = 0; gg < 8; ++gg) {
      g0[gg] = cvtpk(e0[2 * gg], e0[2 * gg + 1]);
      g1[gg] = cvtpk(e1[2 * gg], e1[2 * gg + 1]);
    }
    bf16x8 pb[4];
    {
      unsigned a, c2, b2, d2;
      a = g0[0]; b2 = g0[2]; swap32(a, b2);
      c2 = g0[1]; d2 = g0[3]; swap32(c2, d2);
      pb[0] = mkfrag(a, c2, b2, d2);
      a = g0[4]; b2 = g0[6]; swap32(a, b2);
      c2 = g0[5]; d2 = g0[7]; swap32(c2, d2);
      pb[1] = mkfrag(a, c2, b2, d2);
      a = g1[0]; b2 = g1[2]; swap32(a, b2);
      c2 = g1[1]; d2 = g1[3]; swap32(c2, d2);
      pb[2] = mkfrag(a, c2, b2, d2);
      a = g1[4]; b2 = g1[6]; swap32(a, b2);
      c2 = g1[5]; d2 = g1[7]; swap32(c2, d2);
      pb[3] = mkfrag(a, c2, b2, d2);
    }

    // ---- O^T += V^T · P^T ----
#pragma unroll
    for (int ks = 0; ks < 4; ++ks) {
      const int cidx = (((2 * ks + hi) ^ (col & 7)) << 3);
      bf16x8 vf0 = *(const bf16x8*)&sm.kv.Vl[cur][col * 64 + cidx];
      bf16x8 vf1 = *(const bf16x8*)&sm.kv.Vl[cur][(col + 32) * 64 + cidx];
      ot0 = __builtin_amdgcn_mfma_f32_32x32x16_bf16(vf0, pb[ks], ot0, 0, 0, 0);
      ot1 = __builtin_amdgcn_mfma_f32_32x32x16_bf16(vf1, pb[ks], ot1, 0, 0, 0);
    }

    // ---- stage next tile into the other buffer ----
    if (it + 1 < NT) {
      __syncthreads();
      *(bf16x8*)&sm.kv.Kl[cur ^ 1][koff0] = pk0;
      *(bf16x8*)&sm.kv.Kl[cur ^ 1][koff1] = pk1;
      *(bf16x8*)&sm.kv.Vl[cur ^ 1][koff0] = pv0;
      *(bf16x8*)&sm.kv.Vl[cur ^ 1][koff1] = pv1;
      __syncthreads();
    }
  }

  __syncthreads();  // all waves done with K/V LDS before Ol aliasing write

  // ---- epilogue: transpose via LDS, coalesced store ----
  const float inv = (SPLITS == 1) ? (1.0f / l_) : 1.0f;
#pragma unroll
  for (int r = 0; r < 16; ++r) {
    const int dvb = (r & 3) + 8 * (r >> 2) + 4 * hi;
    sm.Ol[w][col][dvb] = f2bf(ot0[r] * inv);
    sm.Ol[w][col][dvb + 32] = f2bf(ot1[r] * inv);
  }
  if (SPLITS == 2 && hi == 0) {
    float2 mm = {m_, l_};
    *(float2*)&ml[((size_t)(sp * 16 + bh) * NS + q0 + col) * 2] = mm;
  }
  asm volatile("s_waitcnt lgkmcnt(0)" ::: "memory");
  const int row = lane >> 1;
#pragma unroll
  for (int p = 0; p < 4; ++p) {
    const int chunk = (lane & 1) + 2 * p;
    bf16x8 vv = *(const bf16x8*)&sm.Ol[w][row][chunk * 8];
    if (SPLITS == 1)
      *(bf16x8*)&cc[((size_t)(b * NS + q0 + row)) * 512 + h * 64 + chunk * 8] = vv;
    else
      *(bf16x8*)&op[((size_t)(sp * 16 + bh) * NS + q0 + row) * 64 + chunk * 8] = vv;
  }
}

// ---- combine two KV-split partials -> cc ----
__global__ void combine_kernel(const unsigned short* __restrict__ op,
                               const float* __restrict__ ml,
                               unsigned short* __restrict__ cc) {
  const int id = blockIdx.x * 256 + threadIdx.x;  // 524288 total
  const int chunk = id & 7;
  const int qq = (id >> 3) & 4095;
  const int bh = id >> 15;
  const int b = bh >> 3, h = bh & 7;
  const float2 ml0 = *(const float2*)&ml[((size_t)bh * NS + qq) * 2];
  const float2 ml1 = *(const float2*)&ml[((size_t)(16 + bh) * NS + qq) * 2];
  const float m = fmaxf(ml0.x, ml1.x);
  const float w0 = exp2_hw(ml0.x - m), w1 = exp2_hw(ml1.x - m);
  const float invl = 1.0f / (ml0.y * w0 + ml1.y * w1);
  const bf16x8 o0 =
      *(const bf16x8*)&op[((size_t)bh * NS + qq) * 64 + chunk * 8];
  const bf16x8 o1 =
      *(const bf16x8*)&op[((size_t)(16 + bh) * NS + qq) * 64 + chunk * 8];
  bf16x8 out;
#pragma unroll
  for (int j = 0; j < 8; ++j) {
    const float v = (bf2f((unsigned short)o0[j]) * w0 +
                     bf2f((unsigned short)o1[j]) * w1) * invl;
    out[j] = (short)f2bf(v);
  }
  *(bf16x8*)&cc[((size_t)(b * NS + qq)) * 512 + h * 64 + chunk * 8] = out;
}

extern "C" void kernel_launch(void* const* d_in, const int* in_sizes, int n_in,
                              void* d_out, int out_size, void* d_ws, size_t ws_size,
                              hipStream_t stream) {
  const float* x  = (const float*)d_in[0];
  const float* Wq = (const float*)d_in[1];
  const float* bq = (const float*)d_in[2];
  const float* Wk = (const float*)d_in[3];
  const float* bk = (const float*)d_in[4];
  const float* Wv = (const float*)d_in[5];
  const float* bv = (const float*)d_in[6];
  const float* Wo = (const float*)d_in[7];
  const float* bo = (const float*)d_in[8];

  unsigned char* ws = (unsigned char*)d_ws;
  unsigned short* x_bf = (unsigned short*)(ws);              // 8 MB [8192][512]
  unsigned short* w3   = (unsigned short*)(ws + 8388608);    // 1.5 MB
  unsigned short* wo_t = (unsigned short*)(ws + 9961472);    // 0.5 MB
  unsigned short* qb   = (unsigned short*)(ws + 10485760);   // 8 MB [16][4096][64]
  unsigned short* kb   = (unsigned short*)(ws + 18874368);   // 8 MB
  unsigned short* vb   = (unsigned short*)(ws + 27262976);   // 8 MB [16][64][4096]
  unsigned short* op   = (unsigned short*)(ws + 35651584);   // 16 MB [2][16][4096][64]
  float*          mlp  = (float*)(ws + 52428800);            // 1 MB [2][16][4096][2]
  unsigned short* cc   = x_bf;  // reuse: x_bf dead after QKV GEMM

  const bool two_split = ws_size >= 53477376ull;

  pack_kernel<<<8192, 256, 0, stream>>>(x, Wq, Wk, Wv, Wo, x_bf, w3, wo_t);
  gemm_bt<0><<<dim3(64, 12), 256, 0, stream>>>(x_bf, w3, bq, bk, bv, qb, kb, vb,
                                               nullptr);
  if (two_split) {
    attn_kernel<2><<<dim3(32, 32), 256, 0, stream>>>(qb, kb, vb, nullptr, op,
                                                     mlp);
    combine_kernel<<<2048, 256, 0, stream>>>(op, mlp, cc);
  } else {
    attn_kernel<1><<<dim3(32, 16), 256, 0, stream>>>(qb, kb, vb, cc, nullptr,
                                                     nullptr);
  }
  gemm_bt<1><<<dim3(64, 4), 256, 0, stream>>>(cc, wo_t, bo, nullptr, nullptr,
                                              nullptr, nullptr, nullptr,
                                              (float*)d_out);
}

// Round 5
// 153.919 us; speedup vs baseline: 1.0432x; 1.0432x over previous
//
#include <hip/hip_runtime.h>
#include <hip/hip_bf16.h>

typedef __attribute__((ext_vector_type(8))) short bf16x8;
typedef __attribute__((ext_vector_type(4))) float f32x4;
typedef __attribute__((ext_vector_type(16))) float f32x16;
typedef __attribute__((ext_vector_type(4))) unsigned short u16x4;
typedef __attribute__((ext_vector_type(4))) unsigned int u32x4;

#define NB 2
#define NS 4096
#define ND 512
#define NH 8

__device__ __forceinline__ unsigned short f2bf(float f) {
  unsigned int u = __float_as_uint(f);
  u += 0x7fffu + ((u >> 16) & 1u);
  return (unsigned short)(u >> 16);
}

__device__ __forceinline__ float bf2f(unsigned short h) {
  return __uint_as_float(((unsigned)h) << 16);
}

__device__ __forceinline__ float exp2_hw(float x) {
  float r;
  asm("v_exp_f32 %0, %1" : "=v"(r) : "v"(x));
  return r;
}

__device__ __forceinline__ unsigned cvtpk(float lo, float hi) {
  unsigned r;
  asm("v_cvt_pk_bf16_f32 %0, %1, %2" : "=v"(r) : "v"(lo), "v"(hi));
  return r;
}

__device__ __forceinline__ void swap32(unsigned& a, unsigned& b) {
  asm("v_permlane32_swap_b32 %0, %1" : "+v"(a), "+v"(b));
}

__device__ __forceinline__ bf16x8 mkfrag(unsigned w0, unsigned w1,
                                         unsigned w2, unsigned w3) {
  u32x4 u = {w0, w1, w2, w3};
  return __builtin_bit_cast(bf16x8, u);
}

// async global->LDS DMA, 16B per lane; dest = wave-uniform base + lane*16
__device__ __forceinline__ void gload_lds16(const unsigned short* g,
                                            unsigned short* l) {
  __builtin_amdgcn_global_load_lds(
      (const __attribute__((address_space(1))) unsigned int*)g,
      (__attribute__((address_space(3))) unsigned int*)l, 16, 0, 0);
}

// ---------------- pack: fp32 -> bf16, pre-transpose weights ----------------
__global__ void pack_kernel(const float* __restrict__ x,
                            const float* __restrict__ Wq,
                            const float* __restrict__ Wk,
                            const float* __restrict__ Wv,
                            const float* __restrict__ Wo,
                            unsigned short* __restrict__ x_bf,
                            unsigned short* __restrict__ w3,    // [3*512][512]
                            unsigned short* __restrict__ wo_t)  // [512][512]
{
  int idx = blockIdx.x * 256 + threadIdx.x;
  const int NX4 = NB * NS * ND / 4;  // 1048576 float4s
  const int NW = 512 * 512;          // 262144
  if (idx < NX4) {
    const float4 f = ((const float4*)x)[idx];
    u16x4 o;
    o[0] = f2bf(f.x); o[1] = f2bf(f.y); o[2] = f2bf(f.z); o[3] = f2bf(f.w);
    ((u16x4*)x_bf)[idx] = o;
  } else if (idx < NX4 + 3 * NW) {
    int j = idx - NX4;
    int p = j / NW;
    int r = j - p * NW;
    int n = r >> 9, d = r & 511;
    int h = n >> 6, o = n & 63;
    const float* W = (p == 0) ? Wq : (p == 1) ? Wk : Wv;
    w3[j] = f2bf(W[(h * 512 + d) * 64 + o]);
  } else if (idx < NX4 + 4 * NW) {
    int j = idx - NX4 - 3 * NW;
    int n = j >> 9, kk = j & 511;
    wo_t[j] = f2bf(Wo[kk * 512 + n]);
  }
}

// ---------------- GEMM: C[m][n] = sum_k A[m][k]*Bm[n][k], K=512 ------------
template <int MODE>
__global__ void gemm_bt(const unsigned short* __restrict__ A,
                        const unsigned short* __restrict__ Bm,
                        const float* __restrict__ b0,
                        const float* __restrict__ b1,
                        const float* __restrict__ b2,
                        unsigned short* __restrict__ qo,
                        unsigned short* __restrict__ ko,
                        unsigned short* __restrict__ vo,
                        float* __restrict__ fo) {
  __shared__ unsigned short Al[128 * 32];
  __shared__ unsigned short Bl[128 * 32];
  const int t = threadIdx.x;
  const int m0 = blockIdx.x * 128;
  const int n0 = blockIdx.y * 128;
  const int lane = t & 63;
  const int w = t >> 6;
  const int wm = w >> 1, wn = w & 1;
  const int c = lane & 15, g = lane >> 4;

  f32x4 acc[4][4];
#pragma unroll
  for (int i = 0; i < 4; ++i)
#pragma unroll
    for (int j = 0; j < 4; ++j) acc[i][j] = (f32x4){0.f, 0.f, 0.f, 0.f};

  const int srow = t >> 1, sseg = (t & 1) * 16;
  const unsigned short* Ap = A + (size_t)(m0 + srow) * 512 + sseg;
  const unsigned short* Bp = Bm + (size_t)(n0 + srow) * 512 + sseg;
  unsigned short* Alp = &Al[srow * 32 + sseg];
  unsigned short* Blp = &Bl[srow * 32 + sseg];

  for (int k0 = 0; k0 < 512; k0 += 32) {
    bf16x8 ra0 = *(const bf16x8*)(Ap + k0);
    bf16x8 ra1 = *(const bf16x8*)(Ap + k0 + 8);
    bf16x8 rb0 = *(const bf16x8*)(Bp + k0);
    bf16x8 rb1 = *(const bf16x8*)(Bp + k0 + 8);
    __syncthreads();
    *(bf16x8*)(Alp) = ra0;
    *(bf16x8*)(Alp + 8) = ra1;
    *(bf16x8*)(Blp) = rb0;
    *(bf16x8*)(Blp + 8) = rb1;
    __syncthreads();
    bf16x8 af[4], bfr[4];
#pragma unroll
    for (int mf = 0; mf < 4; ++mf)
      af[mf] = *(const bf16x8*)&Al[(wm * 64 + mf * 16 + c) * 32 + g * 8];
#pragma unroll
    for (int nf = 0; nf < 4; ++nf)
      bfr[nf] = *(const bf16x8*)&Bl[(wn * 64 + nf * 16 + c) * 32 + g * 8];
#pragma unroll
    for (int mf = 0; mf < 4; ++mf)
#pragma unroll
      for (int nf = 0; nf < 4; ++nf)
        acc[mf][nf] = __builtin_amdgcn_mfma_f32_16x16x32_bf16(
            af[mf], bfr[nf], acc[mf][nf], 0, 0, 0);
  }

  if (MODE == 0) {
    const int proj = n0 >> 9;  // 0=q,1=k,2=v
    const float* bias = proj == 0 ? b0 : (proj == 1 ? b1 : b2);
    unsigned short* dst01 = proj == 0 ? qo : ko;
    // q pre-scale folds 1/sqrt(64) AND log2(e) so attention can use exp2
    const float scale = proj == 0 ? 0.18033688011112042f : 1.0f;
#pragma unroll
    for (int nf = 0; nf < 4; ++nf) {
      const int col5 = (n0 + wn * 64 + nf * 16 + c) & 511;
      const int h = col5 >> 6, o = col5 & 63;
      const float bb = bias[col5];
#pragma unroll
      for (int mf = 0; mf < 4; ++mf) {
#pragma unroll
        for (int r = 0; r < 4; ++r) {
          const int m = m0 + wm * 64 + mf * 16 + g * 4 + r;
          const int b = m >> 12, s = m & 4095;
          const unsigned short hb = f2bf((acc[mf][nf][r] + bb) * scale);
          if (proj < 2)
            dst01[((size_t)((b * NH + h) * NS + s)) * 64 + o] = hb;
          else
            vo[((size_t)((b * NH + h) * 64 + o)) * NS + s] = hb;
        }
      }
    }
  } else {
#pragma unroll
    for (int nf = 0; nf < 4; ++nf) {
      const int col = n0 + wn * 64 + nf * 16 + c;
      const float bb = b0[col];
#pragma unroll
      for (int mf = 0; mf < 4; ++mf) {
#pragma unroll
        for (int r = 0; r < 4; ++r) {
          const int m = m0 + wm * 64 + mf * 16 + g * 4 + r;
          fo[(size_t)m * 512 + col] = acc[mf][nf][r] + bb;
        }
      }
    }
  }
}

// online softmax + P->bf16 fragments for one qset (32 q-cols x 64 keys/lane)
__device__ __forceinline__ void softmax_qset(f32x16& pA, f32x16& pB,
                                             float& m_, float& l_,
                                             f32x16& o0, f32x16& o1,
                                             bf16x8* pb) {
  float a[8];
#pragma unroll
  for (int r = 0; r < 8; ++r)
    a[r] = fmaxf(fmaxf(pA[r], pA[r + 8]), fmaxf(pB[r], pB[r + 8]));
  float pm = fmaxf(fmaxf(fmaxf(a[0], a[1]), fmaxf(a[2], a[3])),
                   fmaxf(fmaxf(a[4], a[5]), fmaxf(a[6], a[7])));
  pm = fmaxf(pm, __shfl_xor(pm, 32, 64));
  if (__any(pm > m_ + 8.f)) {  // defer-max
    const float resc = exp2_hw(m_ - pm);
    m_ = pm;
    l_ *= resc;
#pragma unroll
    for (int r = 0; r < 16; ++r) { o0[r] *= resc; o1[r] *= resc; }
  }
#pragma unroll
  for (int r = 0; r < 16; ++r) {
    pA[r] = exp2_hw(pA[r] - m_);
    pB[r] = exp2_hw(pB[r] - m_);
  }
  float s[8];
#pragma unroll
  for (int r = 0; r < 8; ++r)
    s[r] = (pA[r] + pA[r + 8]) + (pB[r] + pB[r + 8]);
  float rs = ((s[0] + s[1]) + (s[2] + s[3])) + ((s[4] + s[5]) + (s[6] + s[7]));
  rs += __shfl_xor(rs, 32, 64);
  l_ += rs;
  unsigned g0[8], g1[8];
#pragma unroll
  for (int gg = 0; gg < 8; ++gg) {
    g0[gg] = cvtpk(pA[2 * gg], pA[2 * gg + 1]);
    g1[gg] = cvtpk(pB[2 * gg], pB[2 * gg + 1]);
  }
  unsigned a1, b1, c1, d1;
  a1 = g0[0]; b1 = g0[2]; swap32(a1, b1);
  c1 = g0[1]; d1 = g0[3]; swap32(c1, d1);
  pb[0] = mkfrag(a1, c1, b1, d1);
  a1 = g0[4]; b1 = g0[6]; swap32(a1, b1);
  c1 = g0[5]; d1 = g0[7]; swap32(c1, d1);
  pb[1] = mkfrag(a1, c1, b1, d1);
  a1 = g1[0]; b1 = g1[2]; swap32(a1, b1);
  c1 = g1[1]; d1 = g1[3]; swap32(c1, d1);
  pb[2] = mkfrag(a1, c1, b1, d1);
  a1 = g1[4]; b1 = g1[6]; swap32(a1, b1);
  c1 = g1[5]; d1 = g1[7]; swap32(c1, d1);
  pb[3] = mkfrag(a1, c1, b1, d1);
}

// ------- flash attention v5: 64 q-rows/wave, DMA-staged K/V, split-KV -----
// Block = 4 waves x 64 q-rows = 256 rows; KVBLK=64, double-buffered LDS.
// QK^T: S^T = mfma(A=K, B=Q) per qset; softmax lane-local; O^T = V^T.P^T.
template <int SPLITS>
__global__ __launch_bounds__(256, 2) void attn_kernel(
    const unsigned short* __restrict__ q,     // [bh][s][64] (pre-scaled)
    const unsigned short* __restrict__ k,     // [bh][s][64]
    const unsigned short* __restrict__ vt,    // [bh][64][s]
    unsigned short* __restrict__ cc,          // [b][s][512]      (SPLITS=1)
    unsigned short* __restrict__ op,          // [sp][bh][s][64]  (SPLITS=2)
    float* __restrict__ ml)                   // [sp][bh][s][2]   (SPLITS=2)
{
  union SMemU {
    struct { unsigned short Kl[2][4096]; unsigned short Vl[2][4096]; } kv;
    unsigned short Ol[4][32][68];  // epilogue transpose (K/V dead by then)
  };
  __shared__ SMemU sm;
  const int t = threadIdx.x;
  const int w = t >> 6, lane = t & 63;
  const int col = lane & 31, hi = lane >> 5;
  const int bh = blockIdx.y & 15;
  const int sp = blockIdx.y >> 4;
  const int b = bh >> 3, h = bh & 7;
  const int q0 = blockIdx.x * 256 + w * 64;  // this wave's 64 q-rows
  const int kbase = sp * (NS / SPLITS);

  const unsigned short* qh = q + (size_t)bh * NS * 64;
  const unsigned short* kh = k + (size_t)bh * NS * 64;
  const unsigned short* vh = vt + (size_t)bh * 64 * NS;

  // Q as B-operand, 2 qsets: lane: qrow = q0 + qs*32 + col, d = 16c + 8hi + j
  bf16x8 qf[2][4];
#pragma unroll
  for (int qs = 0; qs < 2; ++qs)
#pragma unroll
    for (int c = 0; c < 4; ++c)
      qf[qs][c] = *(const bf16x8*)&qh[(size_t)(q0 + qs * 32 + col) * 64 +
                                      c * 16 + hi * 8];

  // DMA staging: per wave 4 x gload_lds16 (K rows w*16..+15, V d-rows same).
  // Pre-swizzled GLOBAL source (chunk ^ row&7) + linear LDS dest keeps the
  // proven XOR layout: LDS[row][ch] = G[row][ch ^ (row&7)].
  const int rl = lane >> 3, chn = lane & 7;
  const int lk = rl * 64 + ((chn ^ (rl & 7)) << 3);   // shorts
  const int lv = rl * NS + ((chn ^ (rl & 7)) << 3);   // shorts

  f32x16 ot[4];  // [qs*2 + dhalf]
#pragma unroll
  for (int i = 0; i < 4; ++i)
#pragma unroll
    for (int r = 0; r < 16; ++r) ot[i][r] = 0.f;
  float m_[2] = {-1.0e30f, -1.0e30f}, l_[2] = {0.f, 0.f};

  const int NT = NS / (64 * SPLITS);

  {  // prologue: stage tile 0 into buffer 0
    const unsigned short* gk = kh + (size_t)(kbase + w * 16) * 64;
    const unsigned short* gv = vh + (size_t)(w * 16) * NS + kbase;
    gload_lds16(gk + lk, &sm.kv.Kl[0][w * 1024]);
    gload_lds16(gk + lk + 512, &sm.kv.Kl[0][w * 1024 + 512]);
    gload_lds16(gv + lv, &sm.kv.Vl[0][w * 1024]);
    gload_lds16(gv + lv + 8 * NS, &sm.kv.Vl[0][w * 1024 + 512]);
    __syncthreads();  // compiler drains vmcnt before barrier
  }

  for (int it = 0; it < NT; ++it) {
    const int cur = it & 1;
    if (it + 1 < NT) {  // issue next-tile DMA; drains at end-of-iter barrier
      const unsigned short* gk =
          kh + (size_t)(kbase + (it + 1) * 64 + w * 16) * 64;
      const unsigned short* gv =
          vh + (size_t)(w * 16) * NS + kbase + (it + 1) * 64;
      gload_lds16(gk + lk, &sm.kv.Kl[cur ^ 1][w * 1024]);
      gload_lds16(gk + lk + 512, &sm.kv.Kl[cur ^ 1][w * 1024 + 512]);
      gload_lds16(gv + lv, &sm.kv.Vl[cur ^ 1][w * 1024]);
      gload_lds16(gv + lv + 8 * NS, &sm.kv.Vl[cur ^ 1][w * 1024 + 512]);
    }

    // ---- K fragments (8 x ds_read_b128), QK^T for both qsets ----
    bf16x8 kfr[2][4];
#pragma unroll
    for (int c = 0; c < 4; ++c) {
      const int cidx = (((2 * c + hi) ^ (col & 7)) << 3);
      kfr[0][c] = *(const bf16x8*)&sm.kv.Kl[cur][col * 64 + cidx];
      kfr[1][c] = *(const bf16x8*)&sm.kv.Kl[cur][(col + 32) * 64 + cidx];
    }
    f32x16 p0, p1, p2, p3;
#pragma unroll
    for (int r = 0; r < 16; ++r) { p0[r] = 0.f; p1[r] = 0.f; p2[r] = 0.f; p3[r] = 0.f; }
    __builtin_amdgcn_s_setprio(1);
#pragma unroll
    for (int c = 0; c < 4; ++c) {
      p0 = __builtin_amdgcn_mfma_f32_32x32x16_bf16(kfr[0][c], qf[0][c], p0, 0, 0, 0);
      p1 = __builtin_amdgcn_mfma_f32_32x32x16_bf16(kfr[1][c], qf[0][c], p1, 0, 0, 0);
      p2 = __builtin_amdgcn_mfma_f32_32x32x16_bf16(kfr[0][c], qf[1][c], p2, 0, 0, 0);
      p3 = __builtin_amdgcn_mfma_f32_32x32x16_bf16(kfr[1][c], qf[1][c], p3, 0, 0, 0);
    }
    __builtin_amdgcn_s_setprio(0);

    // ---- V fragments issued early (latency hides under softmax) ----
    bf16x8 vfr[2][4];
#pragma unroll
    for (int ks = 0; ks < 4; ++ks) {
      const int cidx = (((2 * ks + hi) ^ (col & 7)) << 3);
      vfr[0][ks] = *(const bf16x8*)&sm.kv.Vl[cur][col * 64 + cidx];
      vfr[1][ks] = *(const bf16x8*)&sm.kv.Vl[cur][(col + 32) * 64 + cidx];
    }

    // ---- qset0: softmax + PV ----
    bf16x8 pb[4];
    softmax_qset(p0, p1, m_[0], l_[0], ot[0], ot[1], pb);
    __builtin_amdgcn_s_setprio(1);
#pragma unroll
    for (int ks = 0; ks < 4; ++ks) {
      ot[0] = __builtin_amdgcn_mfma_f32_32x32x16_bf16(vfr[0][ks], pb[ks], ot[0], 0, 0, 0);
      ot[1] = __builtin_amdgcn_mfma_f32_32x32x16_bf16(vfr[1][ks], pb[ks], ot[1], 0, 0, 0);
    }
    __builtin_amdgcn_s_setprio(0);

    // ---- qset1: softmax + PV ----
    softmax_qset(p2, p3, m_[1], l_[1], ot[2], ot[3], pb);
    __builtin_amdgcn_s_setprio(1);
#pragma unroll
    for (int ks = 0; ks < 4; ++ks) {
      ot[2] = __builtin_amdgcn_mfma_f32_32x32x16_bf16(vfr[0][ks], pb[ks], ot[2], 0, 0, 0);
      ot[3] = __builtin_amdgcn_mfma_f32_32x32x16_bf16(vfr[1][ks], pb[ks], ot[3], 0, 0, 0);
    }
    __builtin_amdgcn_s_setprio(0);

    __syncthreads();  // drains this iter's DMA (vmcnt) + orders LDS reuse
  }

  // ---- epilogue: per qset, normalize + transpose via LDS, coalesced store --
#pragma unroll
  for (int qs = 0; qs < 2; ++qs) {
    const float inv = (SPLITS == 1) ? (1.0f / l_[qs]) : 1.0f;
#pragma unroll
    for (int r = 0; r < 16; ++r) {
      const int dvb = (r & 3) + 8 * (r >> 2) + 4 * hi;
      sm.Ol[w][col][dvb] = f2bf(ot[qs * 2][r] * inv);
      sm.Ol[w][col][dvb + 32] = f2bf(ot[qs * 2 + 1][r] * inv);
    }
    if (SPLITS == 2 && hi == 0) {
      float2 mm = {m_[qs], l_[qs]};
      *(float2*)&ml[((size_t)(sp * 16 + bh) * NS + q0 + qs * 32 + col) * 2] = mm;
    }
    asm volatile("s_waitcnt lgkmcnt(0)" ::: "memory");
    const int row = lane >> 1;
#pragma unroll
    for (int p = 0; p < 4; ++p) {
      const int chunk = (lane & 1) + 2 * p;
      bf16x8 vv = *(const bf16x8*)&sm.Ol[w][row][chunk * 8];
      if (SPLITS == 1)
        *(bf16x8*)&cc[((size_t)(b * NS + q0 + qs * 32 + row)) * 512 + h * 64 +
                      chunk * 8] = vv;
      else
        *(bf16x8*)&op[((size_t)(sp * 16 + bh) * NS + q0 + qs * 32 + row) * 64 +
                      chunk * 8] = vv;
    }
    asm volatile("s_waitcnt lgkmcnt(0)" ::: "memory");  // WAR before next qset
  }
}

// ---- combine two KV-split partials -> cc ----
__global__ void combine_kernel(const unsigned short* __restrict__ op,
                               const float* __restrict__ ml,
                               unsigned short* __restrict__ cc) {
  const int id = blockIdx.x * 256 + threadIdx.x;  // 524288 total
  const int chunk = id & 7;
  const int qq = (id >> 3) & 4095;
  const int bh = id >> 15;
  const int b = bh >> 3, h = bh & 7;
  const float2 ml0 = *(const float2*)&ml[((size_t)bh * NS + qq) * 2];
  const float2 ml1 = *(const float2*)&ml[((size_t)(16 + bh) * NS + qq) * 2];
  const float m = fmaxf(ml0.x, ml1.x);
  const float w0 = exp2_hw(ml0.x - m), w1 = exp2_hw(ml1.x - m);
  const float invl = 1.0f / (ml0.y * w0 + ml1.y * w1);
  const bf16x8 o0 =
      *(const bf16x8*)&op[((size_t)bh * NS + qq) * 64 + chunk * 8];
  const bf16x8 o1 =
      *(const bf16x8*)&op[((size_t)(16 + bh) * NS + qq) * 64 + chunk * 8];
  bf16x8 out;
#pragma unroll
  for (int j = 0; j < 8; ++j) {
    const float v = (bf2f((unsigned short)o0[j]) * w0 +
                     bf2f((unsigned short)o1[j]) * w1) * invl;
    out[j] = (short)f2bf(v);
  }
  *(bf16x8*)&cc[((size_t)(b * NS + qq)) * 512 + h * 64 + chunk * 8] = out;
}

extern "C" void kernel_launch(void* const* d_in, const int* in_sizes, int n_in,
                              void* d_out, int out_size, void* d_ws, size_t ws_size,
                              hipStream_t stream) {
  const float* x  = (const float*)d_in[0];
  const float* Wq = (const float*)d_in[1];
  const float* bq = (const float*)d_in[2];
  const float* Wk = (const float*)d_in[3];
  const float* bk = (const float*)d_in[4];
  const float* Wv = (const float*)d_in[5];
  const float* bv = (const float*)d_in[6];
  const float* Wo = (const float*)d_in[7];
  const float* bo = (const float*)d_in[8];

  unsigned char* ws = (unsigned char*)d_ws;
  unsigned short* x_bf = (unsigned short*)(ws);              // 8 MB [8192][512]
  unsigned short* w3   = (unsigned short*)(ws + 8388608);    // 1.5 MB
  unsigned short* wo_t = (unsigned short*)(ws + 9961472);    // 0.5 MB
  unsigned short* qb   = (unsigned short*)(ws + 10485760);   // 8 MB [16][4096][64]
  unsigned short* kb   = (unsigned short*)(ws + 18874368);   // 8 MB
  unsigned short* vb   = (unsigned short*)(ws + 27262976);   // 8 MB [16][64][4096]
  unsigned short* op   = (unsigned short*)(ws + 35651584);   // 16 MB [2][16][4096][64]
  float*          mlp  = (float*)(ws + 52428800);            // 1 MB [2][16][4096][2]
  unsigned short* cc   = x_bf;  // reuse: x_bf dead after QKV GEMM

  const bool two_split = ws_size >= 53477376ull;

  pack_kernel<<<8192, 256, 0, stream>>>(x, Wq, Wk, Wv, Wo, x_bf, w3, wo_t);
  gemm_bt<0><<<dim3(64, 12), 256, 0, stream>>>(x_bf, w3, bq, bk, bv, qb, kb, vb,
                                               nullptr);
  if (two_split) {
    attn_kernel<2><<<dim3(16, 32), 256, 0, stream>>>(qb, kb, vb, nullptr, op,
                                                     mlp);
    combine_kernel<<<2048, 256, 0, stream>>>(op, mlp, cc);
  } else {
    attn_kernel<1><<<dim3(16, 16), 256, 0, stream>>>(qb, kb, vb, cc, nullptr,
                                                     nullptr);
  }
  gemm_bt<1><<<dim3(64, 4), 256, 0, stream>>>(cc, wo_t, bo, nullptr, nullptr,
                                              nullptr, nullptr, nullptr,
                                              (float*)d_out);
}